// Round 11
// baseline (244.220 us; speedup 1.0000x reference)
//
#include <hip/hip_runtime.h>
#include <cmath>

#define N_NODES 4096
#define FDIM    256
#define CDIM    40
#define NEDGE   131072
#define CAP     256                  // ELL row capacity (row nnz ~Poisson(64))
#define HBITS   19
#define HSIZE   (1 << HBITS)         // 512K hash slots, load <= 0.25
#define TWO_PI_F 6.28318530717958647692f

typedef __bf16 bf16;
typedef __bf16 bf16x2 __attribute__((ext_vector_type(2)));
typedef __bf16 bf16x4 __attribute__((ext_vector_type(4)));
typedef __bf16 bf16x8 __attribute__((ext_vector_type(8)));
typedef _Float16 f16;
typedef _Float16 f16x2 __attribute__((ext_vector_type(2)));
typedef float  f32x4  __attribute__((ext_vector_type(4)));
typedef unsigned char u8;

static constexpr size_t NF = (size_t)N_NODES * FDIM;      // 1,048,576

// Entry carries PRE-PACKED half2 coefficient pairs:
//   ab = (lr, -li), ba = (li, lr)  so that per complex feature (xr,xi):
//   ar += dot2(ab, x)   ai += dot2(ba, x)   -- one instruction each.
// All-zero Entry (from memset padding) contributes exactly 0 and gathers
// row 0 (L2-hot) -- padded entries are pipelined and effectively free.
struct __align__(16) Entry { unsigned ab, ba; int col, pad; };

__device__ __forceinline__ unsigned pack_h2(float a, float b) {
    f16x2 h; h[0] = (f16)a; h[1] = (f16)b;
    return __builtin_bit_cast(unsigned, h);
}
__device__ __forceinline__ f16x2 bch2(unsigned u) {
    return __builtin_bit_cast(f16x2, u);
}

// RNE f32 -> fp8 e5m2 (e5m2 == top byte of f16, round-to-nearest-even)
__device__ __forceinline__ unsigned f32_to_e5m2(float v) {
    unsigned short h = __builtin_bit_cast(unsigned short, (f16)v);
    return ((unsigned)h + 0x7Fu + (((unsigned)h >> 8) & 1u)) >> 8 & 0xFFu;
}

// decode 2 packed e5m2 (low 2 bytes of u) -> f16x2 via byte permute
__device__ __forceinline__ f16x2 e5m2_pair_lo(unsigned u) {
    return bch2(__builtin_amdgcn_perm(u, 0u, 0x05000400u));
}
__device__ __forceinline__ f16x2 e5m2_pair_hi(unsigned u) {
    return bch2(__builtin_amdgcn_perm(u, 0u, 0x07000600u));
}

// 2-way f16 dot product with f32 accumulate: d = a.x*b.x + a.y*b.y + c
__device__ __forceinline__ float fdot2(f16x2 a, f16x2 b, float c) {
#if __has_builtin(__builtin_amdgcn_fdot2)
    return __builtin_amdgcn_fdot2(a, b, c, false);
#else
    asm("v_dot2_f32_f16 %0, %1, %2, %0" : "+v"(c) : "v"(a), "v"(b));
    return c;
#endif
}

// async global->LDS, 16B per lane: src = per-lane gaddr, dest = uniform base
__device__ __forceinline__ void gld_lds16(const void* g, void* s) {
    __builtin_amdgcn_global_load_lds(
        (const __attribute__((address_space(1))) void*)g,
        (__attribute__((address_space(3))) void*)s,
        16, 0, 0);
}

__device__ __forceinline__ unsigned cell_hash(unsigned cell) {
    return (cell * 2654435761u) >> (32 - HBITS);
}

// ---------------------------------------------------------------------------
// 1. Fused prep: blocks [0,512) hash-insert edges (+row/col sums);
//    blocks [512, 512+4096) cast X -> planar bf16 + interleaved fp8;
//    remaining blocks cast W1/W2 -> transposed bf16 and Wc -> padded bf16.
// ---------------------------------------------------------------------------
#define NWT (256 * 768)
#define HASH_BLOCKS ((NEDGE + 255) / 256)            // 512
#define XCAST_BLOCKS ((int)(NF / 256))               // 4096
#define WCAST_BLOCKS ((2 * NWT + 48 * 512) / 256)    // 1632
__global__ __launch_bounds__(256) void prep_k(
    const int* __restrict__ edges, const float* __restrict__ ew,
    int* __restrict__ hkey, float* __restrict__ hval,
    float* __restrict__ rowsum, float* __restrict__ colsum,
    const float* __restrict__ Xr, const float* __restrict__ Xi,
    const float* __restrict__ W1, const float* __restrict__ W2,
    const float* __restrict__ Wc,
    bf16* __restrict__ Xr16, bf16* __restrict__ Xi16, u8* __restrict__ XC8,
    bf16* __restrict__ W1t, bf16* __restrict__ W2t, bf16* __restrict__ Wcb) {
    int bid = blockIdx.x;
    if (bid < HASH_BLOCKS) {
        int e = bid * 256 + threadIdx.x;
        if (e >= NEDGE) return;
        int r = edges[e], c = edges[NEDGE + e];
        float wv = ew[e];
        atomicAdd(rowsum + r, wv);
        atomicAdd(colsum + c, wv);
        unsigned cell = (unsigned)r * N_NODES + c;      // < 2^24
        unsigned h = cell_hash(cell);
        for (;;) {
            int old = atomicCAS(hkey + h, 0, (int)(cell + 1));
            if (old == 0 || old == (int)(cell + 1)) { atomicAdd(hval + h, wv); break; }
            h = (h + 1) & (HSIZE - 1);
        }
    } else if (bid < HASH_BLOCKS + XCAST_BLOCKS) {
        int idx = (bid - HASH_BLOCKS) * 256 + threadIdx.x;   // n*256+f
        float vr = Xr[idx], vi = Xi[idx];
        Xr16[idx] = (bf16)vr; Xi16[idx] = (bf16)vi;
        unsigned pr = f32_to_e5m2(vr), pi = f32_to_e5m2(vi);
        ((unsigned short*)XC8)[idx] = (unsigned short)(pr | (pi << 8));
    } else {
        int idx = (bid - HASH_BLOCKS - XCAST_BLOCKS) * 256 + threadIdx.x;
        if (idx < 2 * NWT) {
            const float* W = (idx < NWT) ? W1 : W2;
            bf16* Wt = (idx < NWT) ? W1t : W2t;
            int id = (idx < NWT) ? idx : idx - NWT;
            int nout = id / 768, kk = id - nout * 768;
            int o = kk >> 8, k = kk & 255;
            Wt[id] = (bf16)W[((size_t)o * 256 + k) * 256 + nout];
        } else {
            int id = idx - 2 * NWT;
            int row = id >> 9, k = id & 511;
            Wcb[id] = (row < CDIM) ? (bf16)Wc[row * 512 + k] : (bf16)0.f;
        }
    }
}

// ---------------------------------------------------------------------------
// 2. Hash -> ELL, dinv inlined; coefficients packed to half2 pairs.
//    ent is pre-zeroed; slots beyond cnt[i] stay zero (ELL padding).
// ---------------------------------------------------------------------------
__global__ __launch_bounds__(256) void hash_to_ell(
    const int* __restrict__ hkey, const float* __restrict__ hval,
    const float* __restrict__ rowsum, const float* __restrict__ colsum,
    const float* __restrict__ qptr,
    int* __restrict__ cnt, Entry* __restrict__ ent) {
    int h = blockIdx.x * 256 + threadIdx.x;
    int k = hkey[h];
    if (k == 0) return;
    unsigned cell = (unsigned)(k - 1);
    int i = cell >> 12, j = cell & 4095;
    float a = hval[h];
    float b = 0.f;
    bool mirror = false;
    if (i == j) { b = a; mirror = true; }
    else {
        unsigned mcell = (unsigned)j * N_NODES + i;
        unsigned hh = cell_hash(mcell);
        for (;;) {
            int kk = hkey[hh];
            if (kk == (int)(mcell + 1)) { b = hval[hh]; mirror = true; break; }
            if (kk == 0) break;
            hh = (hh + 1) & (HSIZE - 1);
        }
    }
    float di = 0.5f * (rowsum[i] + colsum[i]); if (di == 0.f) di = 1.f;
    float dj = 0.5f * (rowsum[j] + colsum[j]); if (dj == 0.f) dj = 1.f;
    float an = 0.5f * (a + b) / sqrtf(di * dj);
    float s, c;
    sincosf(TWO_PI_F * qptr[0] * (a - b), &s, &c);
    float lr = -an * c;
    float li = an * s;                 // for (i,j); conjugate uses -li
    int pos = atomicAdd(cnt + i, 1);
    if (pos < CAP) {
        Entry en; en.ab = pack_h2(lr, -li); en.ba = pack_h2(li, lr);
        en.col = j; en.pad = 0;
        ent[(size_t)i * CAP + pos] = en;
    }
    if (!mirror) {   // emit conjugate cell (j,i): (lr, -li)
        int pos2 = atomicAdd(cnt + j, 1);
        if (pos2 < CAP) {
            Entry en; en.ab = pack_h2(lr, li); en.ba = pack_h2(-li, lr);
            en.col = i; en.pad = 0;
            ent[(size_t)j * CAP + pos2] = en;
        }
    }
}

// ---------------------------------------------------------------------------
// 3. Sparse complex SpMM (ELL), v12: PAIRED global_load_lds GATHERS.
//    One gld_lds16 fetches TWO entries' fp8 rows (lanes 0-31 -> row A,
//    lanes 32-63 -> row B) into a per-wave LDS buffer -- halving the VMEM
//    instruction count (the measured serializing resource, ~26cy/instr).
//    Per-wave batches of 4 paired loads; no inter-wave sync in the loop
//    (each wave owns its 4KB staging region). MACs read staged rows via
//    ds_read_b64 (DS pipe, off the critical VMEM path).
// ---------------------------------------------------------------------------
__global__ __launch_bounds__(256) void spmm_k(
    const int* __restrict__ cnt, const Entry* __restrict__ ent,
    const u8* __restrict__ XC8,
    const bf16* __restrict__ C0r, const bf16* __restrict__ C0i,
    float alpha, float beta,
    bf16* __restrict__ Zr, bf16* __restrict__ Zi, u8* __restrict__ ZC8)
{
    __shared__ __align__(16) Entry sent[CAP];        // 4 KB
    __shared__ __align__(16) u8 sx[4][4096];         // 16 KB (4KB per wave)
    __shared__ f32x4 redR[3][64];                    // 3 KB
    __shared__ f32x4 redI[3][64];                    // 3 KB

    const int wave = threadIdx.x >> 6, lane = threadIdx.x & 63;
    const int row = blockIdx.x;
    int n1 = cnt[row]; if (n1 > CAP) n1 = CAP;
    int n1r = (n1 + 31) & ~31;                       // multiple of 32, <= CAP
    const Entry* erow = ent + (size_t)row * CAP;

    // stage this row's entries (incl. zero padding): wave w -> [w*64, w*64+64)
    if (wave * 64 < n1r)
        gld_lds16(erow + wave * 64 + lane, sent + wave * 64);
    __syncthreads();                                 // drains vmcnt+lgkmcnt

    u8* sxw = sx[wave];
    const int lsel = (lane & 31) * 16;               // byte offset within a row
    float ar[4] = {}, ai[4] = {};
    const int nu = n1r >> 2;                         // entries per wave (mult of 8)

    for (int ub = 0; ub < nu; ub += 8) {
        // issue 4 paired gathers (8 entries) -- 4 VMEM instructions
        #pragma unroll
        for (int p = 0; p < 4; ++p) {
            int eA = wave + 4 * (ub + 2 * p);
            int eB = eA + 4;
            int colA = sent[eA].col & 4095;
            int colB = sent[eB].col & 4095;
            int col = (lane < 32) ? colA : colB;
            gld_lds16(XC8 + (size_t)col * 512 + lsel, sxw + p * 1024);
        }
        asm volatile("s_waitcnt vmcnt(0)" ::: "memory");
        __builtin_amdgcn_sched_barrier(0);
        // consume the 8 staged rows
        #pragma unroll
        for (int p = 0; p < 4; ++p) {
            #pragma unroll
            for (int h = 0; h < 2; ++h) {
                int e = wave + 4 * (ub + 2 * p + h);
                Entry en = sent[e];
                uint2 xd = *(const uint2*)(sxw + p * 1024 + h * 512 + lane * 8);
                f16x2 ab = bch2(en.ab), ba = bch2(en.ba);
                f16x2 c0 = e5m2_pair_lo(xd.x), c1 = e5m2_pair_hi(xd.x);
                f16x2 c2 = e5m2_pair_lo(xd.y), c3 = e5m2_pair_hi(xd.y);
                ar[0] = fdot2(ab, c0, ar[0]); ai[0] = fdot2(ba, c0, ai[0]);
                ar[1] = fdot2(ab, c1, ar[1]); ai[1] = fdot2(ba, c1, ai[1]);
                ar[2] = fdot2(ab, c2, ar[2]); ai[2] = fdot2(ba, c2, ai[2]);
                ar[3] = fdot2(ab, c3, ar[3]); ai[3] = fdot2(ba, c3, ai[3]);
            }
        }
        // all ds_reads of sxw retired before next batch overwrites it
        asm volatile("s_waitcnt lgkmcnt(0)" ::: "memory");
        __builtin_amdgcn_sched_barrier(0);
    }

    if (wave != 0) {
        f32x4 r, i;
        #pragma unroll
        for (int c = 0; c < 4; ++c) { r[c] = ar[c]; i[c] = ai[c]; }
        redR[wave - 1][lane] = r;
        redI[wave - 1][lane] = i;
    }
    __syncthreads();
    if (wave != 0) return;

    #pragma unroll
    for (int w = 0; w < 3; ++w) {
        f32x4 r = redR[w][lane], i = redI[w][lane];
        #pragma unroll
        for (int c = 0; c < 4; ++c) { ar[c] += r[c]; ai[c] += i[c]; }
    }

    size_t pbase = (size_t)row * FDIM + lane * 4;
    float vr[4], vi[4];
    if (beta != 0.f) {
        bf16x4 cr = *(const bf16x4*)&C0r[pbase];
        bf16x4 ci = *(const bf16x4*)&C0i[pbase];
        #pragma unroll
        for (int c = 0; c < 4; ++c) {
            vr[c] = alpha * ar[c] + beta * (float)cr[c];
            vi[c] = alpha * ai[c] + beta * (float)ci[c];
        }
    } else {
        #pragma unroll
        for (int c = 0; c < 4; ++c) { vr[c] = alpha * ar[c]; vi[c] = alpha * ai[c]; }
    }
    bf16x4 pr, pi;
    #pragma unroll
    for (int c = 0; c < 4; ++c) { pr[c] = (bf16)vr[c]; pi[c] = (bf16)vi[c]; }
    *(bf16x4*)&Zr[pbase] = pr;
    *(bf16x4*)&Zi[pbase] = pi;
    if (ZC8) {
        uint2 o;
        o.x = f32_to_e5m2(vr[0]) | (f32_to_e5m2(vi[0]) << 8) |
              (f32_to_e5m2(vr[1]) << 16) | (f32_to_e5m2(vi[1]) << 24);
        o.y = f32_to_e5m2(vr[2]) | (f32_to_e5m2(vi[2]) << 8) |
              (f32_to_e5m2(vr[3]) << 16) | (f32_to_e5m2(vi[3]) << 24);
        *(uint2*)&ZC8[(size_t)row * 512 + lane * 8] = o;
    }
}

// ---------------------------------------------------------------------------
// 4. wapply via MFMA (unchanged).
// ---------------------------------------------------------------------------
__global__ __launch_bounds__(256) void wapply_mfma(
    const bf16* __restrict__ Z0r, const bf16* __restrict__ Z0i,
    const bf16* __restrict__ Z1r, const bf16* __restrict__ Z1i,
    const bf16* __restrict__ Z2r, const bf16* __restrict__ Z2i,
    const bf16* __restrict__ Wt,      // [256][768]
    const float* __restrict__ bias,   // [256]
    bf16* __restrict__ O16r_r, bf16* __restrict__ O16r_i,
    u8* __restrict__ OC8)
{
    __shared__ __align__(16) bf16 sZr[32 * 32];
    __shared__ __align__(16) bf16 sZi[32 * 32];
    __shared__ __align__(16) bf16 sW [64 * 32];

    const int tid  = threadIdx.x;
    const int wave = tid >> 6;
    const int lane = tid & 63;
    const int rowBase = blockIdx.y * 32;
    const int colBase = blockIdx.x * 64;

    const int srow = lane >> 2;          // 0..15
    const int skc  = (lane & 3) * 8;

    f32x4 accSr[2] = {}, accSi[2] = {};
    const int fr = lane & 15;
    const int fk = (lane >> 4) * 8;

    for (int kb = 0; kb < 3 * FDIM; kb += 32) {
        int order = kb >> 8;
        int kloc  = kb & 255;
        if (wave == 0 || wave == 1) {
            const bf16* z;
            if (wave == 0) z = (order == 0) ? Z0r : (order == 1) ? Z1r : Z2r;
            else           z = (order == 0) ? Z0i : (order == 1) ? Z1i : Z2i;
            bf16* s = (wave == 0) ? sZr : sZi;
            const bf16* g = z + (size_t)(rowBase + srow) * FDIM + kloc + skc;
            #pragma unroll
            for (int t = 0; t < 2; ++t)
                gld_lds16(g + (size_t)t * 16 * FDIM, s + t * 512);
        } else if (wave == 2) {
            const bf16* g = Wt + (size_t)(colBase + srow) * 768 + kb + skc;
            #pragma unroll
            for (int t = 0; t < 4; ++t)
                gld_lds16(g + (size_t)t * 16 * 768, sW + t * 512);
        }
        __syncthreads();

        bf16x8 zr[2], zi[2], wv;
        #pragma unroll
        for (int m = 0; m < 2; ++m) {
            int r = m * 16 + fr;
            zr[m] = *(const bf16x8*)&sZr[r * 32 + fk];
            zi[m] = *(const bf16x8*)&sZi[r * 32 + fk];
        }
        wv = *(const bf16x8*)&sW[(wave * 16 + fr) * 32 + fk];
        #pragma unroll
        for (int m = 0; m < 2; ++m) {
            accSr[m] = __builtin_amdgcn_mfma_f32_16x16x32_bf16(zr[m], wv, accSr[m], 0, 0, 0);
            accSi[m] = __builtin_amdgcn_mfma_f32_16x16x32_bf16(zi[m], wv, accSi[m], 0, 0, 0);
        }
        __syncthreads();
    }

    #pragma unroll
    for (int m = 0; m < 2; ++m) {
        int row0 = rowBase + m * 16 + (lane >> 4) * 4;
        int col  = colBase + wave * 16 + fr;
        float bv = bias[col];
        #pragma unroll
        for (int r = 0; r < 4; ++r) {
            float vr = bv - accSi[m][r];
            float vi = bv + accSr[m][r];
            int row = row0 + r;
            size_t idx = (size_t)row * FDIM + col;
            if (O16r_r) {
                O16r_r[idx] = (bf16)vr; O16r_i[idx] = (bf16)vi;
            }
            if (OC8) {
                unsigned pr = f32_to_e5m2(vr), pi = f32_to_e5m2(vi);
                ((unsigned short*)OC8)[idx] = (unsigned short)(pr | (pi << 8));
            }
        }
    }
}

// ---------------------------------------------------------------------------
// 5. Head via MFMA + fused log_softmax (unchanged).
// ---------------------------------------------------------------------------
__global__ __launch_bounds__(256) void head_mfma(
    const bf16* __restrict__ Yrb,
    const bf16* __restrict__ Yib,
    const bf16* __restrict__ Wcb,
    const float* __restrict__ bc,
    float* __restrict__ out)          // [4096][40]
{
    __shared__ __align__(16) bf16 sY[64][72];
    __shared__ __align__(16) bf16 sW[48][72];
    __shared__ float sS[64][52];

    const int tid  = threadIdx.x;
    const int wave = tid >> 6;
    const int lane = tid & 63;
    const int r0 = blockIdx.x * 64;

    f32x4 acc[3] = {};

    for (int kb = 0; kb < 512; kb += 64) {
        const bf16* src = (kb < 256) ? Yrb : Yib;
        const int koff = kb & 255;
        #pragma unroll
        for (int e = 0; e < 2; ++e) {
            int idx = tid + e * 256;             // 0..511
            int rr = idx >> 3, kk = (idx & 7) * 8;
            *(bf16x8*)&sY[rr][kk] =
                *(const bf16x8*)&src[(size_t)(r0 + rr) * FDIM + koff + kk];
        }
        #pragma unroll
        for (int e = 0; e < 2; ++e) {
            int idx = tid + e * 256;             // need 0..383
            if (idx < 384) {
                int rr = idx >> 3, kk = (idx & 7) * 8;
                *(bf16x8*)&sW[rr][kk] =
                    *(const bf16x8*)&Wcb[(size_t)rr * 512 + kb + kk];
            }
        }
        __syncthreads();
        #pragma unroll
        for (int ks = 0; ks < 2; ++ks) {
            bf16x8 a = *(const bf16x8*)&sY[wave * 16 + (lane & 15)][ks * 32 + (lane >> 4) * 8];
            #pragma unroll
            for (int n = 0; n < 3; ++n) {
                bf16x8 b = *(const bf16x8*)&sW[n * 16 + (lane & 15)][ks * 32 + (lane >> 4) * 8];
                acc[n] = __builtin_amdgcn_mfma_f32_16x16x32_bf16(a, b, acc[n], 0, 0, 0);
            }
        }
        __syncthreads();
    }

    #pragma unroll
    for (int n = 0; n < 3; ++n) {
        int col = n * 16 + (lane & 15);
        int rloc = wave * 16 + (lane >> 4) * 4;
        #pragma unroll
        for (int r = 0; r < 4; ++r)
            sS[rloc + r][col] = acc[n][r];
    }
    __syncthreads();

    if (tid < 64) {
        float mx = -INFINITY;
        #pragma unroll 8
        for (int c = 0; c < CDIM; ++c) {
            float lv = sS[tid][c] + bc[c];
            sS[tid][c] = lv;
            mx = fmaxf(mx, lv);
        }
        float se = 0.f;
        #pragma unroll 8
        for (int c = 0; c < CDIM; ++c) se += expf(sS[tid][c] - mx);
        float lse = mx + logf(se);
        #pragma unroll 8
        for (int c = 0; c < CDIM; ++c)
            out[(size_t)(r0 + tid) * CDIM + c] = sS[tid][c] - lse;
    }
}

// ---------------------------------------------------------------------------
// Launcher
// ---------------------------------------------------------------------------
extern "C" void kernel_launch(void* const* d_in, const int* in_sizes, int n_in,
                              void* d_out, int out_size, void* d_ws, size_t ws_size,
                              hipStream_t stream) {
    const float* real = (const float*)d_in[0];
    const float* imag = (const float*)d_in[1];
    const int*   edges = (const int*)d_in[2];
    const float* q    = (const float*)d_in[3];
    const float* ew   = (const float*)d_in[4];
    const float* W1   = (const float*)d_in[5];
    const float* b1   = (const float*)d_in[6];
    const float* W2   = (const float*)d_in[7];
    const float* b2   = (const float*)d_in[8];
    const float* Wc   = (const float*)d_in[9];
    const float* bc   = (const float*)d_in[10];
    float* out = (float*)d_out;

    // ---- workspace carve-up ----
    // Zeroed region: hkey, hval, cnt, rowsum, colsum, ent (ELL zero-padding).
    char* w = (char*)d_ws;
    int*      hkey   = (int*)w;   w += (size_t)HSIZE * 4;       // 2 MB
    float*    hval   = (float*)w; w += (size_t)HSIZE * 4;       // 2 MB
    int*      cnt    = (int*)w;   w += N_NODES * 4;
    float*    rowsum = (float*)w; w += N_NODES * 4;
    float*    colsum = (float*)w; w += N_NODES * 4;
    Entry*    ent    = (Entry*)w; w += (size_t)N_NODES * CAP * 16;  // 16 MB
    size_t zero_bytes = (size_t)((char*)w - (char*)d_ws);
    // Non-zeroed:
    bf16* Xr16 = (bf16*)w; w += NF * 2;
    bf16* Xi16 = (bf16*)w; w += NF * 2;
    u8*   XC8  = (u8*)w;   w += NF * 2;                         // interleaved fp8
    bf16* Z1r  = (bf16*)w; w += NF * 2;
    bf16* Z1i  = (bf16*)w; w += NF * 2;
    u8*   Z1C8 = (u8*)w;   w += NF * 2;
    bf16* Z2r  = (bf16*)w; w += NF * 2;
    bf16* Z2i  = (bf16*)w; w += NF * 2;
    bf16* Y1rb = (bf16*)w; w += NF * 2;
    bf16* Y1ib = (bf16*)w; w += NF * 2;
    u8*   Y1C8 = (u8*)w;   w += NF * 2;
    bf16* Y2rb = (bf16*)w; w += NF * 2;
    bf16* Y2ib = (bf16*)w; w += NF * 2;
    bf16* W1t  = (bf16*)w; w += 256 * 768 * 2;
    bf16* W2t  = (bf16*)w; w += 256 * 768 * 2;
    bf16* Wcb  = (bf16*)w; w += 48 * 512 * 2;

    hipMemsetAsync(d_ws, 0, zero_bytes, stream);

    // ---- fused prep (hash insert + all casts) ----
    prep_k<<<HASH_BLOCKS + XCAST_BLOCKS + WCAST_BLOCKS, 256, 0, stream>>>(
        edges, ew, hkey, hval, rowsum, colsum,
        real, imag, W1, W2, Wc,
        Xr16, Xi16, XC8, W1t, W2t, Wcb);

    hash_to_ell<<<HSIZE / 256, 256, 0, stream>>>(hkey, hval, rowsum, colsum,
                                                 q, cnt, ent);

    dim3 gW(FDIM / 64, N_NODES / 32);   // (4, 128) -> 512 blocks, 2/CU

    // ---- Layer 1 ----
    spmm_k<<<N_NODES, 256, 0, stream>>>(cnt, ent, XC8, nullptr, nullptr,
                                        1.f, 0.f, Z1r, Z1i, Z1C8);
    spmm_k<<<N_NODES, 256, 0, stream>>>(cnt, ent, Z1C8, Xr16, Xi16,
                                        2.f, -1.f, Z2r, Z2i, nullptr);
    wapply_mfma<<<gW, 256, 0, stream>>>(Xr16, Xi16, Z1r, Z1i, Z2r, Z2i,
                                        W1t, b1,
                                        Y1rb, Y1ib,
                                        Y1C8);

    // ---- Layer 2 ----
    spmm_k<<<N_NODES, 256, 0, stream>>>(cnt, ent, Y1C8, nullptr, nullptr,
                                        1.f, 0.f, Z1r, Z1i, Z1C8);
    spmm_k<<<N_NODES, 256, 0, stream>>>(cnt, ent, Z1C8, Y1rb, Y1ib,
                                        2.f, -1.f, Z2r, Z2i, nullptr);
    wapply_mfma<<<gW, 256, 0, stream>>>(Y1rb, Y1ib, Z1r, Z1i, Z2r, Z2i,
                                        W2t, b2,
                                        Y2rb, Y2ib,
                                        nullptr);

    // ---- Head ----
    head_mfma<<<64, 256, 0, stream>>>(Y2rb, Y2ib, Wcb, bc, out);
}

// Round 12
// 240.322 us; speedup vs baseline: 1.0162x; 1.0162x over previous
//
#include <hip/hip_runtime.h>
#include <cmath>

#define N_NODES 4096
#define FDIM    256
#define CDIM    40
#define NEDGE   131072
#define CAP     256                  // ELL row capacity (row nnz ~Poisson(64))
#define HBITS   19
#define HSIZE   (1 << HBITS)         // 512K hash slots, load <= 0.25
#define TWO_PI_F 6.28318530717958647692f

typedef __bf16 bf16;
typedef __bf16 bf16x2 __attribute__((ext_vector_type(2)));
typedef __bf16 bf16x4 __attribute__((ext_vector_type(4)));
typedef __bf16 bf16x8 __attribute__((ext_vector_type(8)));
typedef _Float16 f16;
typedef _Float16 f16x2 __attribute__((ext_vector_type(2)));
typedef float  f32x4  __attribute__((ext_vector_type(4)));
typedef unsigned char u8;

static constexpr size_t NF = (size_t)N_NODES * FDIM;      // 1,048,576

// Entry carries PRE-PACKED half2 coefficient pairs:
//   ab = (lr, -li), ba = (li, lr)  so that per complex feature (xr,xi):
//   ar += dot2(ab, x)   ai += dot2(ba, x)   -- one instruction each.
// All-zero Entry (from memset padding) contributes exactly 0 and gathers
// row 0 (L2-hot) -- padded entries are pipelined and effectively free.
struct __align__(16) Entry { unsigned ab, ba; int col, pad; };

__device__ __forceinline__ unsigned pack_h2(float a, float b) {
    f16x2 h; h[0] = (f16)a; h[1] = (f16)b;
    return __builtin_bit_cast(unsigned, h);
}
__device__ __forceinline__ f16x2 bch2(unsigned u) {
    return __builtin_bit_cast(f16x2, u);
}

// RNE f32 -> fp8 e5m2 (e5m2 == top byte of f16, round-to-nearest-even)
__device__ __forceinline__ unsigned f32_to_e5m2(float v) {
    unsigned short h = __builtin_bit_cast(unsigned short, (f16)v);
    return ((unsigned)h + 0x7Fu + (((unsigned)h >> 8) & 1u)) >> 8 & 0xFFu;
}

// decode 2 packed e5m2 (low 2 bytes of u) -> f16x2 via byte permute
__device__ __forceinline__ f16x2 e5m2_pair_lo(unsigned u) {
    return bch2(__builtin_amdgcn_perm(u, 0u, 0x05000400u));
}
__device__ __forceinline__ f16x2 e5m2_pair_hi(unsigned u) {
    return bch2(__builtin_amdgcn_perm(u, 0u, 0x07000600u));
}

// 2-way f16 dot product with f32 accumulate: d = a.x*b.x + a.y*b.y + c
__device__ __forceinline__ float fdot2(f16x2 a, f16x2 b, float c) {
#if __has_builtin(__builtin_amdgcn_fdot2)
    return __builtin_amdgcn_fdot2(a, b, c, false);
#else
    asm("v_dot2_f32_f16 %0, %1, %2, %0" : "+v"(c) : "v"(a), "v"(b));
    return c;
#endif
}

// async global->LDS, 16B per lane: src = per-lane gaddr, dest = uniform base
__device__ __forceinline__ void gld_lds16(const void* g, void* s) {
    __builtin_amdgcn_global_load_lds(
        (const __attribute__((address_space(1))) void*)g,
        (__attribute__((address_space(3))) void*)s,
        16, 0, 0);
}

__device__ __forceinline__ unsigned cell_hash(unsigned cell) {
    return (cell * 2654435761u) >> (32 - HBITS);
}

// ---------------------------------------------------------------------------
// 1. Fused prep: blocks [0,512) hash-insert edges (+row/col sums);
//    blocks [512, 512+4096) cast X -> planar bf16 + interleaved fp8;
//    remaining blocks cast W1/W2 -> transposed bf16 and Wc -> padded bf16.
// ---------------------------------------------------------------------------
#define NWT (256 * 768)
#define HASH_BLOCKS ((NEDGE + 255) / 256)            // 512
#define XCAST_BLOCKS ((int)(NF / 256))               // 4096
#define WCAST_BLOCKS ((2 * NWT + 48 * 512) / 256)    // 1632
__global__ __launch_bounds__(256) void prep_k(
    const int* __restrict__ edges, const float* __restrict__ ew,
    int* __restrict__ hkey, float* __restrict__ hval,
    float* __restrict__ rowsum, float* __restrict__ colsum,
    const float* __restrict__ Xr, const float* __restrict__ Xi,
    const float* __restrict__ W1, const float* __restrict__ W2,
    const float* __restrict__ Wc,
    bf16* __restrict__ Xr16, bf16* __restrict__ Xi16, u8* __restrict__ XC8,
    bf16* __restrict__ W1t, bf16* __restrict__ W2t, bf16* __restrict__ Wcb) {
    int bid = blockIdx.x;
    if (bid < HASH_BLOCKS) {
        int e = bid * 256 + threadIdx.x;
        if (e >= NEDGE) return;
        int r = edges[e], c = edges[NEDGE + e];
        float wv = ew[e];
        atomicAdd(rowsum + r, wv);
        atomicAdd(colsum + c, wv);
        unsigned cell = (unsigned)r * N_NODES + c;      // < 2^24
        unsigned h = cell_hash(cell);
        for (;;) {
            int old = atomicCAS(hkey + h, 0, (int)(cell + 1));
            if (old == 0 || old == (int)(cell + 1)) { atomicAdd(hval + h, wv); break; }
            h = (h + 1) & (HSIZE - 1);
        }
    } else if (bid < HASH_BLOCKS + XCAST_BLOCKS) {
        int idx = (bid - HASH_BLOCKS) * 256 + threadIdx.x;   // n*256+f
        float vr = Xr[idx], vi = Xi[idx];
        Xr16[idx] = (bf16)vr; Xi16[idx] = (bf16)vi;
        unsigned pr = f32_to_e5m2(vr), pi = f32_to_e5m2(vi);
        ((unsigned short*)XC8)[idx] = (unsigned short)(pr | (pi << 8));
    } else {
        int idx = (bid - HASH_BLOCKS - XCAST_BLOCKS) * 256 + threadIdx.x;
        if (idx < 2 * NWT) {
            const float* W = (idx < NWT) ? W1 : W2;
            bf16* Wt = (idx < NWT) ? W1t : W2t;
            int id = (idx < NWT) ? idx : idx - NWT;
            int nout = id / 768, kk = id - nout * 768;
            int o = kk >> 8, k = kk & 255;
            Wt[id] = (bf16)W[((size_t)o * 256 + k) * 256 + nout];
        } else {
            int id = idx - 2 * NWT;
            int row = id >> 9, k = id & 511;
            Wcb[id] = (row < CDIM) ? (bf16)Wc[row * 512 + k] : (bf16)0.f;
        }
    }
}

// ---------------------------------------------------------------------------
// 2. Hash -> ELL, dinv inlined; coefficients packed to half2 pairs.
//    ent is pre-zeroed; slots beyond cnt[i] stay zero (ELL padding).
// ---------------------------------------------------------------------------
__global__ __launch_bounds__(256) void hash_to_ell(
    const int* __restrict__ hkey, const float* __restrict__ hval,
    const float* __restrict__ rowsum, const float* __restrict__ colsum,
    const float* __restrict__ qptr,
    int* __restrict__ cnt, Entry* __restrict__ ent) {
    int h = blockIdx.x * 256 + threadIdx.x;
    int k = hkey[h];
    if (k == 0) return;
    unsigned cell = (unsigned)(k - 1);
    int i = cell >> 12, j = cell & 4095;
    float a = hval[h];
    float b = 0.f;
    bool mirror = false;
    if (i == j) { b = a; mirror = true; }
    else {
        unsigned mcell = (unsigned)j * N_NODES + i;
        unsigned hh = cell_hash(mcell);
        for (;;) {
            int kk = hkey[hh];
            if (kk == (int)(mcell + 1)) { b = hval[hh]; mirror = true; break; }
            if (kk == 0) break;
            hh = (hh + 1) & (HSIZE - 1);
        }
    }
    float di = 0.5f * (rowsum[i] + colsum[i]); if (di == 0.f) di = 1.f;
    float dj = 0.5f * (rowsum[j] + colsum[j]); if (dj == 0.f) dj = 1.f;
    float an = 0.5f * (a + b) / sqrtf(di * dj);
    float s, c;
    sincosf(TWO_PI_F * qptr[0] * (a - b), &s, &c);
    float lr = -an * c;
    float li = an * s;                 // for (i,j); conjugate uses -li
    int pos = atomicAdd(cnt + i, 1);
    if (pos < CAP) {
        Entry en; en.ab = pack_h2(lr, -li); en.ba = pack_h2(li, lr);
        en.col = j; en.pad = 0;
        ent[(size_t)i * CAP + pos] = en;
    }
    if (!mirror) {   // emit conjugate cell (j,i): (lr, -li)
        int pos2 = atomicAdd(cnt + j, 1);
        if (pos2 < CAP) {
            Entry en; en.ab = pack_h2(lr, li); en.ba = pack_h2(-li, lr);
            en.col = i; en.pad = 0;
            ent[(size_t)j * CAP + pos2] = en;
        }
    }
}

// ---------------------------------------------------------------------------
// 3. Sparse complex SpMM (ELL), v13: PAIRED DIRECT-TO-VGPR GATHERS.
//    One global_load_dwordx4 fetches TWO entries' fp8 rows: lanes 0-31
//    cover row A (16B each), lanes 32-63 cover row B. Halves the VMEM
//    instruction count vs r9 with NO hard waits and NO LDS round-trip
//    (the r11 confounds). Lane l&31 owns features 8l..8l+7 (ar[8]/ai[8]);
//    halves merged via one shfl_xor(32); cross-wave reduce via LDS.
//    Entries LDS-staged (r9); rows zero-padded to 32 (r10) for pairing.
// ---------------------------------------------------------------------------
__global__ __launch_bounds__(256) void spmm_k(
    const int* __restrict__ cnt, const Entry* __restrict__ ent,
    const u8* __restrict__ XC8,
    const bf16* __restrict__ C0r, const bf16* __restrict__ C0i,
    float alpha, float beta,
    bf16* __restrict__ Zr, bf16* __restrict__ Zi, u8* __restrict__ ZC8)
{
    __shared__ __align__(16) Entry sent[CAP];        // 4 KB
    __shared__ float redR[3][32][8];                 // 3 KB
    __shared__ float redI[3][32][8];                 // 3 KB

    const int wave = threadIdx.x >> 6, lane = threadIdx.x & 63;
    const int row = blockIdx.x;
    int n1 = cnt[row]; if (n1 > CAP) n1 = CAP;
    int n1r = (n1 + 31) & ~31;                       // multiple of 32, <= CAP
    const Entry* erow = ent + (size_t)row * CAP;

    // stage this row's entries (incl. zero padding): wave w -> [w*64, w*64+64)
    if (wave * 64 < n1r)
        gld_lds16(erow + wave * 64 + lane, sent + wave * 64);
    __syncthreads();                                 // drains vmcnt+lgkmcnt

    const int hoff = (lane >> 5) << 2;               // +4 entry offset for B-half
    const size_t lsel = (size_t)(lane & 31) * 16;    // byte offset within a row

    float ar[8] = {}, ai[8] = {};
    const int nb = n1r >> 5;                         // batches of 4 pairs
    for (int b = 0; b < nb; ++b) {
        // read 4 pair-entries for this lane's half (ds_read_b128 each)
        Entry en[4];
        #pragma unroll
        for (int p = 0; p < 4; ++p)
            en[p] = sent[wave + 8 * (4 * b + p) + hoff];
        // 4 paired gathers in flight (8 entries total)
        uint4 xv[4];
        #pragma unroll
        for (int p = 0; p < 4; ++p)
            xv[p] = *(const uint4*)(XC8 + (size_t)(en[p].col & 4095) * 512 + lsel);
        #pragma unroll
        for (int p = 0; p < 4; ++p) {
            f16x2 ab = bch2(en[p].ab), ba = bch2(en[p].ba);
            f16x2 c;
            c = e5m2_pair_lo(xv[p].x); ar[0]=fdot2(ab,c,ar[0]); ai[0]=fdot2(ba,c,ai[0]);
            c = e5m2_pair_hi(xv[p].x); ar[1]=fdot2(ab,c,ar[1]); ai[1]=fdot2(ba,c,ai[1]);
            c = e5m2_pair_lo(xv[p].y); ar[2]=fdot2(ab,c,ar[2]); ai[2]=fdot2(ba,c,ai[2]);
            c = e5m2_pair_hi(xv[p].y); ar[3]=fdot2(ab,c,ar[3]); ai[3]=fdot2(ba,c,ai[3]);
            c = e5m2_pair_lo(xv[p].z); ar[4]=fdot2(ab,c,ar[4]); ai[4]=fdot2(ba,c,ai[4]);
            c = e5m2_pair_hi(xv[p].z); ar[5]=fdot2(ab,c,ar[5]); ai[5]=fdot2(ba,c,ai[5]);
            c = e5m2_pair_lo(xv[p].w); ar[6]=fdot2(ab,c,ar[6]); ai[6]=fdot2(ba,c,ai[6]);
            c = e5m2_pair_hi(xv[p].w); ar[7]=fdot2(ab,c,ar[7]); ai[7]=fdot2(ba,c,ai[7]);
        }
    }

    // merge A/B halves: lanes l and l+32 accumulate the SAME features
    #pragma unroll
    for (int k = 0; k < 8; ++k) {
        ar[k] += __shfl_xor(ar[k], 32);
        ai[k] += __shfl_xor(ai[k], 32);
    }

    if (wave != 0 && lane < 32) {
        #pragma unroll
        for (int k = 0; k < 8; ++k) {
            redR[wave - 1][lane][k] = ar[k];
            redI[wave - 1][lane][k] = ai[k];
        }
    }
    __syncthreads();
    if (wave != 0 || lane >= 32) return;

    #pragma unroll
    for (int w = 0; w < 3; ++w)
        #pragma unroll
        for (int k = 0; k < 8; ++k) {
            ar[k] += redR[w][lane][k];
            ai[k] += redI[w][lane][k];
        }

    size_t pbase = (size_t)row * FDIM + lane * 8;    // 8 feats/lane, lanes 0-31
    float vr[8], vi[8];
    if (beta != 0.f) {
        bf16x8 cr = *(const bf16x8*)&C0r[pbase];
        bf16x8 ci = *(const bf16x8*)&C0i[pbase];
        #pragma unroll
        for (int k = 0; k < 8; ++k) {
            vr[k] = alpha * ar[k] + beta * (float)cr[k];
            vi[k] = alpha * ai[k] + beta * (float)ci[k];
        }
    } else {
        #pragma unroll
        for (int k = 0; k < 8; ++k) { vr[k] = alpha * ar[k]; vi[k] = alpha * ai[k]; }
    }
    bf16x8 pr, pi;
    #pragma unroll
    for (int k = 0; k < 8; ++k) { pr[k] = (bf16)vr[k]; pi[k] = (bf16)vi[k]; }
    *(bf16x8*)&Zr[pbase] = pr;
    *(bf16x8*)&Zi[pbase] = pi;
    if (ZC8) {
        uint4 o;
        o.x = f32_to_e5m2(vr[0]) | (f32_to_e5m2(vi[0]) << 8) |
              (f32_to_e5m2(vr[1]) << 16) | (f32_to_e5m2(vi[1]) << 24);
        o.y = f32_to_e5m2(vr[2]) | (f32_to_e5m2(vi[2]) << 8) |
              (f32_to_e5m2(vr[3]) << 16) | (f32_to_e5m2(vi[3]) << 24);
        o.z = f32_to_e5m2(vr[4]) | (f32_to_e5m2(vi[4]) << 8) |
              (f32_to_e5m2(vr[5]) << 16) | (f32_to_e5m2(vi[5]) << 24);
        o.w = f32_to_e5m2(vr[6]) | (f32_to_e5m2(vi[6]) << 8) |
              (f32_to_e5m2(vr[7]) << 16) | (f32_to_e5m2(vi[7]) << 24);
        *(uint4*)&ZC8[(size_t)row * 512 + lane * 16] = o;
    }
}

// ---------------------------------------------------------------------------
// 4. wapply via MFMA (unchanged).
// ---------------------------------------------------------------------------
__global__ __launch_bounds__(256) void wapply_mfma(
    const bf16* __restrict__ Z0r, const bf16* __restrict__ Z0i,
    const bf16* __restrict__ Z1r, const bf16* __restrict__ Z1i,
    const bf16* __restrict__ Z2r, const bf16* __restrict__ Z2i,
    const bf16* __restrict__ Wt,      // [256][768]
    const float* __restrict__ bias,   // [256]
    bf16* __restrict__ O16r_r, bf16* __restrict__ O16r_i,
    u8* __restrict__ OC8)
{
    __shared__ __align__(16) bf16 sZr[32 * 32];
    __shared__ __align__(16) bf16 sZi[32 * 32];
    __shared__ __align__(16) bf16 sW [64 * 32];

    const int tid  = threadIdx.x;
    const int wave = tid >> 6;
    const int lane = tid & 63;
    const int rowBase = blockIdx.y * 32;
    const int colBase = blockIdx.x * 64;

    const int srow = lane >> 2;          // 0..15
    const int skc  = (lane & 3) * 8;

    f32x4 accSr[2] = {}, accSi[2] = {};
    const int fr = lane & 15;
    const int fk = (lane >> 4) * 8;

    for (int kb = 0; kb < 3 * FDIM; kb += 32) {
        int order = kb >> 8;
        int kloc  = kb & 255;
        if (wave == 0 || wave == 1) {
            const bf16* z;
            if (wave == 0) z = (order == 0) ? Z0r : (order == 1) ? Z1r : Z2r;
            else           z = (order == 0) ? Z0i : (order == 1) ? Z1i : Z2i;
            bf16* s = (wave == 0) ? sZr : sZi;
            const bf16* g = z + (size_t)(rowBase + srow) * FDIM + kloc + skc;
            #pragma unroll
            for (int t = 0; t < 2; ++t)
                gld_lds16(g + (size_t)t * 16 * FDIM, s + t * 512);
        } else if (wave == 2) {
            const bf16* g = Wt + (size_t)(colBase + srow) * 768 + kb + skc;
            #pragma unroll
            for (int t = 0; t < 4; ++t)
                gld_lds16(g + (size_t)t * 16 * 768, sW + t * 512);
        }
        __syncthreads();

        bf16x8 zr[2], zi[2], wv;
        #pragma unroll
        for (int m = 0; m < 2; ++m) {
            int r = m * 16 + fr;
            zr[m] = *(const bf16x8*)&sZr[r * 32 + fk];
            zi[m] = *(const bf16x8*)&sZi[r * 32 + fk];
        }
        wv = *(const bf16x8*)&sW[(wave * 16 + fr) * 32 + fk];
        #pragma unroll
        for (int m = 0; m < 2; ++m) {
            accSr[m] = __builtin_amdgcn_mfma_f32_16x16x32_bf16(zr[m], wv, accSr[m], 0, 0, 0);
            accSi[m] = __builtin_amdgcn_mfma_f32_16x16x32_bf16(zi[m], wv, accSi[m], 0, 0, 0);
        }
        __syncthreads();
    }

    #pragma unroll
    for (int m = 0; m < 2; ++m) {
        int row0 = rowBase + m * 16 + (lane >> 4) * 4;
        int col  = colBase + wave * 16 + fr;
        float bv = bias[col];
        #pragma unroll
        for (int r = 0; r < 4; ++r) {
            float vr = bv - accSi[m][r];
            float vi = bv + accSr[m][r];
            int row = row0 + r;
            size_t idx = (size_t)row * FDIM + col;
            if (O16r_r) {
                O16r_r[idx] = (bf16)vr; O16r_i[idx] = (bf16)vi;
            }
            if (OC8) {
                unsigned pr = f32_to_e5m2(vr), pi = f32_to_e5m2(vi);
                ((unsigned short*)OC8)[idx] = (unsigned short)(pr | (pi << 8));
            }
        }
    }
}

// ---------------------------------------------------------------------------
// 5. Head via MFMA + fused log_softmax (unchanged).
// ---------------------------------------------------------------------------
__global__ __launch_bounds__(256) void head_mfma(
    const bf16* __restrict__ Yrb,
    const bf16* __restrict__ Yib,
    const bf16* __restrict__ Wcb,
    const float* __restrict__ bc,
    float* __restrict__ out)          // [4096][40]
{
    __shared__ __align__(16) bf16 sY[64][72];
    __shared__ __align__(16) bf16 sW[48][72];
    __shared__ float sS[64][52];

    const int tid  = threadIdx.x;
    const int wave = tid >> 6;
    const int lane = tid & 63;
    const int r0 = blockIdx.x * 64;

    f32x4 acc[3] = {};

    for (int kb = 0; kb < 512; kb += 64) {
        const bf16* src = (kb < 256) ? Yrb : Yib;
        const int koff = kb & 255;
        #pragma unroll
        for (int e = 0; e < 2; ++e) {
            int idx = tid + e * 256;             // 0..511
            int rr = idx >> 3, kk = (idx & 7) * 8;
            *(bf16x8*)&sY[rr][kk] =
                *(const bf16x8*)&src[(size_t)(r0 + rr) * FDIM + koff + kk];
        }
        #pragma unroll
        for (int e = 0; e < 2; ++e) {
            int idx = tid + e * 256;             // need 0..383
            if (idx < 384) {
                int rr = idx >> 3, kk = (idx & 7) * 8;
                *(bf16x8*)&sW[rr][kk] =
                    *(const bf16x8*)&Wcb[(size_t)rr * 512 + kb + kk];
            }
        }
        __syncthreads();
        #pragma unroll
        for (int ks = 0; ks < 2; ++ks) {
            bf16x8 a = *(const bf16x8*)&sY[wave * 16 + (lane & 15)][ks * 32 + (lane >> 4) * 8];
            #pragma unroll
            for (int n = 0; n < 3; ++n) {
                bf16x8 b = *(const bf16x8*)&sW[n * 16 + (lane & 15)][ks * 32 + (lane >> 4) * 8];
                acc[n] = __builtin_amdgcn_mfma_f32_16x16x32_bf16(a, b, acc[n], 0, 0, 0);
            }
        }
        __syncthreads();
    }

    #pragma unroll
    for (int n = 0; n < 3; ++n) {
        int col = n * 16 + (lane & 15);
        int rloc = wave * 16 + (lane >> 4) * 4;
        #pragma unroll
        for (int r = 0; r < 4; ++r)
            sS[rloc + r][col] = acc[n][r];
    }
    __syncthreads();

    if (tid < 64) {
        float mx = -INFINITY;
        #pragma unroll 8
        for (int c = 0; c < CDIM; ++c) {
            float lv = sS[tid][c] + bc[c];
            sS[tid][c] = lv;
            mx = fmaxf(mx, lv);
        }
        float se = 0.f;
        #pragma unroll 8
        for (int c = 0; c < CDIM; ++c) se += expf(sS[tid][c] - mx);
        float lse = mx + logf(se);
        #pragma unroll 8
        for (int c = 0; c < CDIM; ++c)
            out[(size_t)(r0 + tid) * CDIM + c] = sS[tid][c] - lse;
    }
}

// ---------------------------------------------------------------------------
// Launcher
// ---------------------------------------------------------------------------
extern "C" void kernel_launch(void* const* d_in, const int* in_sizes, int n_in,
                              void* d_out, int out_size, void* d_ws, size_t ws_size,
                              hipStream_t stream) {
    const float* real = (const float*)d_in[0];
    const float* imag = (const float*)d_in[1];
    const int*   edges = (const int*)d_in[2];
    const float* q    = (const float*)d_in[3];
    const float* ew   = (const float*)d_in[4];
    const float* W1   = (const float*)d_in[5];
    const float* b1   = (const float*)d_in[6];
    const float* W2   = (const float*)d_in[7];
    const float* b2   = (const float*)d_in[8];
    const float* Wc   = (const float*)d_in[9];
    const float* bc   = (const float*)d_in[10];
    float* out = (float*)d_out;

    // ---- workspace carve-up ----
    // Zeroed region: hkey, hval, cnt, rowsum, colsum, ent (ELL zero-padding).
    char* w = (char*)d_ws;
    int*      hkey   = (int*)w;   w += (size_t)HSIZE * 4;       // 2 MB
    float*    hval   = (float*)w; w += (size_t)HSIZE * 4;       // 2 MB
    int*      cnt    = (int*)w;   w += N_NODES * 4;
    float*    rowsum = (float*)w; w += N_NODES * 4;
    float*    colsum = (float*)w; w += N_NODES * 4;
    Entry*    ent    = (Entry*)w; w += (size_t)N_NODES * CAP * 16;  // 16 MB
    size_t zero_bytes = (size_t)((char*)w - (char*)d_ws);
    // Non-zeroed:
    bf16* Xr16 = (bf16*)w; w += NF * 2;
    bf16* Xi16 = (bf16*)w; w += NF * 2;
    u8*   XC8  = (u8*)w;   w += NF * 2;                         // interleaved fp8
    bf16* Z1r  = (bf16*)w; w += NF * 2;
    bf16* Z1i  = (bf16*)w; w += NF * 2;
    u8*   Z1C8 = (u8*)w;   w += NF * 2;
    bf16* Z2r  = (bf16*)w; w += NF * 2;
    bf16* Z2i  = (bf16*)w; w += NF * 2;
    bf16* Y1rb = (bf16*)w; w += NF * 2;
    bf16* Y1ib = (bf16*)w; w += NF * 2;
    u8*   Y1C8 = (u8*)w;   w += NF * 2;
    bf16* Y2rb = (bf16*)w; w += NF * 2;
    bf16* Y2ib = (bf16*)w; w += NF * 2;
    bf16* W1t  = (bf16*)w; w += 256 * 768 * 2;
    bf16* W2t  = (bf16*)w; w += 256 * 768 * 2;
    bf16* Wcb  = (bf16*)w; w += 48 * 512 * 2;

    hipMemsetAsync(d_ws, 0, zero_bytes, stream);

    // ---- fused prep (hash insert + all casts) ----
    prep_k<<<HASH_BLOCKS + XCAST_BLOCKS + WCAST_BLOCKS, 256, 0, stream>>>(
        edges, ew, hkey, hval, rowsum, colsum,
        real, imag, W1, W2, Wc,
        Xr16, Xi16, XC8, W1t, W2t, Wcb);

    hash_to_ell<<<HSIZE / 256, 256, 0, stream>>>(hkey, hval, rowsum, colsum,
                                                 q, cnt, ent);

    dim3 gW(FDIM / 64, N_NODES / 32);   // (4, 128) -> 512 blocks, 2/CU

    // ---- Layer 1 ----
    spmm_k<<<N_NODES, 256, 0, stream>>>(cnt, ent, XC8, nullptr, nullptr,
                                        1.f, 0.f, Z1r, Z1i, Z1C8);
    spmm_k<<<N_NODES, 256, 0, stream>>>(cnt, ent, Z1C8, Xr16, Xi16,
                                        2.f, -1.f, Z2r, Z2i, nullptr);
    wapply_mfma<<<gW, 256, 0, stream>>>(Xr16, Xi16, Z1r, Z1i, Z2r, Z2i,
                                        W1t, b1,
                                        Y1rb, Y1ib,
                                        Y1C8);

    // ---- Layer 2 ----
    spmm_k<<<N_NODES, 256, 0, stream>>>(cnt, ent, Y1C8, nullptr, nullptr,
                                        1.f, 0.f, Z1r, Z1i, Z1C8);
    spmm_k<<<N_NODES, 256, 0, stream>>>(cnt, ent, Z1C8, Y1rb, Y1ib,
                                        2.f, -1.f, Z2r, Z2i, nullptr);
    wapply_mfma<<<gW, 256, 0, stream>>>(Y1rb, Y1ib, Z1r, Z1i, Z2r, Z2i,
                                        W2t, b2,
                                        Y2rb, Y2ib,
                                        nullptr);

    // ---- Head ----
    head_mfma<<<64, 256, 0, stream>>>(Y2rb, Y2ib, Wcb, bc, out);
}

// Round 14
// 236.269 us; speedup vs baseline: 1.0337x; 1.0172x over previous
//
#include <hip/hip_runtime.h>
#include <cmath>

#define N_NODES 4096
#define FDIM    256
#define CDIM    40
#define NEDGE   131072
#define CAP     256                  // ELL row capacity (row nnz ~Poisson(64))
#define HBITS   19
#define HSIZE   (1 << HBITS)         // 512K hash slots, load <= 0.25
#define TWO_PI_F 6.28318530717958647692f

typedef __bf16 bf16;
typedef __bf16 bf16x2 __attribute__((ext_vector_type(2)));
typedef __bf16 bf16x4 __attribute__((ext_vector_type(4)));
typedef __bf16 bf16x8 __attribute__((ext_vector_type(8)));
typedef _Float16 f16;
typedef _Float16 f16x2 __attribute__((ext_vector_type(2)));
typedef float  f32x4  __attribute__((ext_vector_type(4)));
typedef unsigned char u8;

static constexpr size_t NF = (size_t)N_NODES * FDIM;      // 1,048,576

// Entry carries PRE-PACKED half2 coefficient pairs:
//   ab = (lr, -li), ba = (li, lr)  so that per complex feature (xr,xi):
//   ar += dot2(ab, x)   ai += dot2(ba, x)   -- one instruction each.
struct __align__(16) Entry { unsigned ab, ba; int col, pad; };

__device__ __forceinline__ unsigned pack_h2(float a, float b) {
    f16x2 h; h[0] = (f16)a; h[1] = (f16)b;
    return __builtin_bit_cast(unsigned, h);
}
__device__ __forceinline__ f16x2 bch2(unsigned u) {
    return __builtin_bit_cast(f16x2, u);
}

// RNE f32 -> fp8 e5m2 (e5m2 == top byte of f16, round-to-nearest-even)
__device__ __forceinline__ unsigned f32_to_e5m2(float v) {
    unsigned short h = __builtin_bit_cast(unsigned short, (f16)v);
    return ((unsigned)h + 0x7Fu + (((unsigned)h >> 8) & 1u)) >> 8 & 0xFFu;
}

// decode 2 packed e5m2 (low 2 bytes of u) -> f16x2 via byte permute
__device__ __forceinline__ f16x2 e5m2_pair_lo(unsigned u) {
    return bch2(__builtin_amdgcn_perm(u, 0u, 0x05000400u));
}
__device__ __forceinline__ f16x2 e5m2_pair_hi(unsigned u) {
    return bch2(__builtin_amdgcn_perm(u, 0u, 0x07000600u));
}

// 2-way f16 dot product with f32 accumulate: d = a.x*b.x + a.y*b.y + c
__device__ __forceinline__ float fdot2(f16x2 a, f16x2 b, float c) {
#if __has_builtin(__builtin_amdgcn_fdot2)
    return __builtin_amdgcn_fdot2(a, b, c, false);
#else
    asm("v_dot2_f32_f16 %0, %1, %2, %0" : "+v"(c) : "v"(a), "v"(b));
    return c;
#endif
}

// async global->LDS, 16B per lane: src = per-lane gaddr, dest = uniform base
__device__ __forceinline__ void gld_lds16(const void* g, void* s) {
    __builtin_amdgcn_global_load_lds(
        (const __attribute__((address_space(1))) void*)g,
        (__attribute__((address_space(3))) void*)s,
        16, 0, 0);
}

__device__ __forceinline__ unsigned cell_hash(unsigned cell) {
    return (cell * 2654435761u) >> (32 - HBITS);
}

// ---------------------------------------------------------------------------
// 1. Fused prep: blocks [0,512) hash-insert edges (+row/col sums);
//    blocks [512, 512+4096) cast X -> planar bf16 + interleaved fp8;
//    remaining blocks cast W1/W2 -> transposed bf16 and Wc -> padded bf16.
// ---------------------------------------------------------------------------
#define NWT (256 * 768)
#define HASH_BLOCKS ((NEDGE + 255) / 256)            // 512
#define XCAST_BLOCKS ((int)(NF / 256))               // 4096
#define WCAST_BLOCKS ((2 * NWT + 48 * 512) / 256)    // 1632
__global__ __launch_bounds__(256) void prep_k(
    const int* __restrict__ edges, const float* __restrict__ ew,
    int* __restrict__ hkey, float* __restrict__ hval,
    float* __restrict__ rowsum, float* __restrict__ colsum,
    const float* __restrict__ Xr, const float* __restrict__ Xi,
    const float* __restrict__ W1, const float* __restrict__ W2,
    const float* __restrict__ Wc,
    bf16* __restrict__ Xr16, bf16* __restrict__ Xi16, u8* __restrict__ XC8,
    bf16* __restrict__ W1t, bf16* __restrict__ W2t, bf16* __restrict__ Wcb) {
    int bid = blockIdx.x;
    if (bid < HASH_BLOCKS) {
        int e = bid * 256 + threadIdx.x;
        if (e >= NEDGE) return;
        int r = edges[e], c = edges[NEDGE + e];
        float wv = ew[e];
        atomicAdd(rowsum + r, wv);
        atomicAdd(colsum + c, wv);
        unsigned cell = (unsigned)r * N_NODES + c;      // < 2^24
        unsigned h = cell_hash(cell);
        for (;;) {
            int old = atomicCAS(hkey + h, 0, (int)(cell + 1));
            if (old == 0 || old == (int)(cell + 1)) { atomicAdd(hval + h, wv); break; }
            h = (h + 1) & (HSIZE - 1);
        }
    } else if (bid < HASH_BLOCKS + XCAST_BLOCKS) {
        int idx = (bid - HASH_BLOCKS) * 256 + threadIdx.x;   // n*256+f
        float vr = Xr[idx], vi = Xi[idx];
        Xr16[idx] = (bf16)vr; Xi16[idx] = (bf16)vi;
        unsigned pr = f32_to_e5m2(vr), pi = f32_to_e5m2(vi);
        ((unsigned short*)XC8)[idx] = (unsigned short)(pr | (pi << 8));
    } else {
        int idx = (bid - HASH_BLOCKS - XCAST_BLOCKS) * 256 + threadIdx.x;
        if (idx < 2 * NWT) {
            const float* W = (idx < NWT) ? W1 : W2;
            bf16* Wt = (idx < NWT) ? W1t : W2t;
            int id = (idx < NWT) ? idx : idx - NWT;
            int nout = id / 768, kk = id - nout * 768;
            int o = kk >> 8, k = kk & 255;
            Wt[id] = (bf16)W[((size_t)o * 256 + k) * 256 + nout];
        } else {
            int id = idx - 2 * NWT;
            int row = id >> 9, k = id & 511;
            Wcb[id] = (row < CDIM) ? (bf16)Wc[row * 512 + k] : (bf16)0.f;
        }
    }
}

// ---------------------------------------------------------------------------
// 2. Hash -> ELL, dinv inlined; coefficients packed to half2 pairs.
// ---------------------------------------------------------------------------
__global__ __launch_bounds__(256) void hash_to_ell(
    const int* __restrict__ hkey, const float* __restrict__ hval,
    const float* __restrict__ rowsum, const float* __restrict__ colsum,
    const float* __restrict__ qptr,
    int* __restrict__ cnt, Entry* __restrict__ ent) {
    int h = blockIdx.x * 256 + threadIdx.x;
    int k = hkey[h];
    if (k == 0) return;
    unsigned cell = (unsigned)(k - 1);
    int i = cell >> 12, j = cell & 4095;
    float a = hval[h];
    float b = 0.f;
    bool mirror = false;
    if (i == j) { b = a; mirror = true; }
    else {
        unsigned mcell = (unsigned)j * N_NODES + i;
        unsigned hh = cell_hash(mcell);
        for (;;) {
            int kk = hkey[hh];
            if (kk == (int)(mcell + 1)) { b = hval[hh]; mirror = true; break; }
            if (kk == 0) break;
            hh = (hh + 1) & (HSIZE - 1);
        }
    }
    float di = 0.5f * (rowsum[i] + colsum[i]); if (di == 0.f) di = 1.f;
    float dj = 0.5f * (rowsum[j] + colsum[j]); if (dj == 0.f) dj = 1.f;
    float an = 0.5f * (a + b) / sqrtf(di * dj);
    float s, c;
    sincosf(TWO_PI_F * qptr[0] * (a - b), &s, &c);
    float lr = -an * c;
    float li = an * s;                 // for (i,j); conjugate uses -li
    int pos = atomicAdd(cnt + i, 1);
    if (pos < CAP) {
        Entry en; en.ab = pack_h2(lr, -li); en.ba = pack_h2(li, lr);
        en.col = j; en.pad = 0;
        ent[(size_t)i * CAP + pos] = en;
    }
    if (!mirror) {   // emit conjugate cell (j,i): (lr, -li)
        int pos2 = atomicAdd(cnt + j, 1);
        if (pos2 < CAP) {
            Entry en; en.ab = pack_h2(lr, li); en.ba = pack_h2(-li, lr);
            en.col = i; en.pad = 0;
            ent[(size_t)j * CAP + pos2] = en;
        }
    }
}

// ---------------------------------------------------------------------------
// 3. Sparse complex SpMM (ELL), v15: r9 structure with a 16-DEEP gather
//    batch. One batch issues ALL of a typical wave's scattered fetches
//    back-to-back (cols pre-read as scalars) -- maximizing concurrent
//    row-fetch round-trips, the surviving bottleneck candidate. Fallback
//    8-deep and single-entry tails preserve r9 behavior for short rows.
// ---------------------------------------------------------------------------
__global__ __launch_bounds__(256) void spmm_k(
    const int* __restrict__ cnt, const Entry* __restrict__ ent,
    const u8* __restrict__ XC8,
    const bf16* __restrict__ C0r, const bf16* __restrict__ C0i,
    float alpha, float beta,
    bf16* __restrict__ Zr, bf16* __restrict__ Zi, u8* __restrict__ ZC8)
{
    __shared__ __align__(16) Entry sent[CAP];        // 4 KB
    __shared__ f32x4 redR[3][64];
    __shared__ f32x4 redI[3][64];

    const int wave = threadIdx.x >> 6, lane = threadIdx.x & 63;
    const int row = blockIdx.x;
    int n1 = cnt[row]; if (n1 > CAP) n1 = CAP;
    const Entry* erow = ent + (size_t)row * CAP;

    // stage this row's entries: wave w stages entries [w*64, w*64+64)
    if (wave * 64 < n1)
        gld_lds16(erow + wave * 64 + lane, sent + wave * 64);
    __syncthreads();                                 // drains vmcnt+lgkmcnt

    float ar[4] = {}, ai[4] = {};
    int e = wave;
    // 16-deep: all gathers of the batch issued before any consumption
    for (; e + 60 < n1; e += 64) {
        int col[16];
        #pragma unroll
        for (int u = 0; u < 16; ++u)
            col[u] = sent[e + 4 * u].col & 4095;
        uint2 xv[16];
        #pragma unroll
        for (int u = 0; u < 16; ++u)
            xv[u] = *(const uint2*)&XC8[(size_t)col[u] * 512 + lane * 8];
        #pragma unroll
        for (int u = 0; u < 16; ++u) {
            Entry en = sent[e + 4 * u];
            f16x2 ab = bch2(en.ab), ba = bch2(en.ba);
            f16x2 c0 = e5m2_pair_lo(xv[u].x), c1 = e5m2_pair_hi(xv[u].x);
            f16x2 c2 = e5m2_pair_lo(xv[u].y), c3 = e5m2_pair_hi(xv[u].y);
            ar[0] = fdot2(ab, c0, ar[0]); ai[0] = fdot2(ba, c0, ai[0]);
            ar[1] = fdot2(ab, c1, ar[1]); ai[1] = fdot2(ba, c1, ai[1]);
            ar[2] = fdot2(ab, c2, ar[2]); ai[2] = fdot2(ba, c2, ai[2]);
            ar[3] = fdot2(ab, c3, ar[3]); ai[3] = fdot2(ba, c3, ai[3]);
        }
    }
    // 8-deep fallback
    for (; e + 28 < n1; e += 32) {
        Entry ee[8];
        #pragma unroll
        for (int u = 0; u < 8; ++u)
            ee[u] = sent[e + 4 * u];
        uint2 xv[8];
        #pragma unroll
        for (int u = 0; u < 8; ++u)
            xv[u] = *(const uint2*)&XC8[(size_t)(ee[u].col & 4095) * 512 + lane * 8];
        #pragma unroll
        for (int u = 0; u < 8; ++u) {
            f16x2 ab = bch2(ee[u].ab), ba = bch2(ee[u].ba);
            f16x2 c0 = e5m2_pair_lo(xv[u].x), c1 = e5m2_pair_hi(xv[u].x);
            f16x2 c2 = e5m2_pair_lo(xv[u].y), c3 = e5m2_pair_hi(xv[u].y);
            ar[0] = fdot2(ab, c0, ar[0]); ai[0] = fdot2(ba, c0, ai[0]);
            ar[1] = fdot2(ab, c1, ar[1]); ai[1] = fdot2(ba, c1, ai[1]);
            ar[2] = fdot2(ab, c2, ar[2]); ai[2] = fdot2(ba, c2, ai[2]);
            ar[3] = fdot2(ab, c3, ar[3]); ai[3] = fdot2(ba, c3, ai[3]);
        }
    }
    // singles tail
    for (; e < n1; e += 4) {
        Entry e0 = sent[e];
        uint2 x0 = *(const uint2*)&XC8[(size_t)(e0.col & 4095) * 512 + lane * 8];
        f16x2 ab = bch2(e0.ab), ba = bch2(e0.ba);
        f16x2 c0 = e5m2_pair_lo(x0.x), c1 = e5m2_pair_hi(x0.x);
        f16x2 c2 = e5m2_pair_lo(x0.y), c3 = e5m2_pair_hi(x0.y);
        ar[0] = fdot2(ab, c0, ar[0]); ai[0] = fdot2(ba, c0, ai[0]);
        ar[1] = fdot2(ab, c1, ar[1]); ai[1] = fdot2(ba, c1, ai[1]);
        ar[2] = fdot2(ab, c2, ar[2]); ai[2] = fdot2(ba, c2, ai[2]);
        ar[3] = fdot2(ab, c3, ar[3]); ai[3] = fdot2(ba, c3, ai[3]);
    }

    if (wave != 0) {
        f32x4 r, i;
        #pragma unroll
        for (int c = 0; c < 4; ++c) { r[c] = ar[c]; i[c] = ai[c]; }
        redR[wave - 1][lane] = r;
        redI[wave - 1][lane] = i;
    }
    __syncthreads();
    if (wave != 0) return;

    #pragma unroll
    for (int w = 0; w < 3; ++w) {
        f32x4 r = redR[w][lane], i = redI[w][lane];
        #pragma unroll
        for (int c = 0; c < 4; ++c) { ar[c] += r[c]; ai[c] += i[c]; }
    }

    size_t pbase = (size_t)row * FDIM + lane * 4;
    float vr[4], vi[4];
    if (beta != 0.f) {
        bf16x4 cr = *(const bf16x4*)&C0r[pbase];
        bf16x4 ci = *(const bf16x4*)&C0i[pbase];
        #pragma unroll
        for (int c = 0; c < 4; ++c) {
            vr[c] = alpha * ar[c] + beta * (float)cr[c];
            vi[c] = alpha * ai[c] + beta * (float)ci[c];
        }
    } else {
        #pragma unroll
        for (int c = 0; c < 4; ++c) { vr[c] = alpha * ar[c]; vi[c] = alpha * ai[c]; }
    }
    bf16x4 pr, pi;
    #pragma unroll
    for (int c = 0; c < 4; ++c) { pr[c] = (bf16)vr[c]; pi[c] = (bf16)vi[c]; }
    *(bf16x4*)&Zr[pbase] = pr;
    *(bf16x4*)&Zi[pbase] = pi;
    if (ZC8) {
        uint2 o;
        o.x = f32_to_e5m2(vr[0]) | (f32_to_e5m2(vi[0]) << 8) |
              (f32_to_e5m2(vr[1]) << 16) | (f32_to_e5m2(vi[1]) << 24);
        o.y = f32_to_e5m2(vr[2]) | (f32_to_e5m2(vi[2]) << 8) |
              (f32_to_e5m2(vr[3]) << 16) | (f32_to_e5m2(vi[3]) << 24);
        *(uint2*)&ZC8[(size_t)row * 512 + lane * 8] = o;
    }
}

// ---------------------------------------------------------------------------
// 4. wapply via MFMA (unchanged).
// ---------------------------------------------------------------------------
__global__ __launch_bounds__(256) void wapply_mfma(
    const bf16* __restrict__ Z0r, const bf16* __restrict__ Z0i,
    const bf16* __restrict__ Z1r, const bf16* __restrict__ Z1i,
    const bf16* __restrict__ Z2r, const bf16* __restrict__ Z2i,
    const bf16* __restrict__ Wt,      // [256][768]
    const float* __restrict__ bias,   // [256]
    bf16* __restrict__ O16r_r, bf16* __restrict__ O16r_i,
    u8* __restrict__ OC8)
{
    __shared__ __align__(16) bf16 sZr[32 * 32];
    __shared__ __align__(16) bf16 sZi[32 * 32];
    __shared__ __align__(16) bf16 sW [64 * 32];

    const int tid  = threadIdx.x;
    const int wave = tid >> 6;
    const int lane = tid & 63;
    const int rowBase = blockIdx.y * 32;
    const int colBase = blockIdx.x * 64;

    const int srow = lane >> 2;          // 0..15
    const int skc  = (lane & 3) * 8;

    f32x4 accSr[2] = {}, accSi[2] = {};
    const int fr = lane & 15;
    const int fk = (lane >> 4) * 8;

    for (int kb = 0; kb < 3 * FDIM; kb += 32) {
        int order = kb >> 8;
        int kloc  = kb & 255;
        if (wave == 0 || wave == 1) {
            const bf16* z;
            if (wave == 0) z = (order == 0) ? Z0r : (order == 1) ? Z1r : Z2r;
            else           z = (order == 0) ? Z0i : (order == 1) ? Z1i : Z2i;
            bf16* s = (wave == 0) ? sZr : sZi;
            const bf16* g = z + (size_t)(rowBase + srow) * FDIM + kloc + skc;
            #pragma unroll
            for (int t = 0; t < 2; ++t)
                gld_lds16(g + (size_t)t * 16 * FDIM, s + t * 512);
        } else if (wave == 2) {
            const bf16* g = Wt + (size_t)(colBase + srow) * 768 + kb + skc;
            #pragma unroll
            for (int t = 0; t < 4; ++t)
                gld_lds16(g + (size_t)t * 16 * 768, sW + t * 512);
        }
        __syncthreads();

        bf16x8 zr[2], zi[2], wv;
        #pragma unroll
        for (int m = 0; m < 2; ++m) {
            int r = m * 16 + fr;
            zr[m] = *(const bf16x8*)&sZr[r * 32 + fk];
            zi[m] = *(const bf16x8*)&sZi[r * 32 + fk];
        }
        wv = *(const bf16x8*)&sW[(wave * 16 + fr) * 32 + fk];
        #pragma unroll
        for (int m = 0; m < 2; ++m) {
            accSr[m] = __builtin_amdgcn_mfma_f32_16x16x32_bf16(zr[m], wv, accSr[m], 0, 0, 0);
            accSi[m] = __builtin_amdgcn_mfma_f32_16x16x32_bf16(zi[m], wv, accSi[m], 0, 0, 0);
        }
        __syncthreads();
    }

    #pragma unroll
    for (int m = 0; m < 2; ++m) {
        int row0 = rowBase + m * 16 + (lane >> 4) * 4;
        int col  = colBase + wave * 16 + fr;
        float bv = bias[col];
        #pragma unroll
        for (int r = 0; r < 4; ++r) {
            float vr = bv - accSi[m][r];
            float vi = bv + accSr[m][r];
            int row = row0 + r;
            size_t idx = (size_t)row * FDIM + col;
            if (O16r_r) {
                O16r_r[idx] = (bf16)vr; O16r_i[idx] = (bf16)vi;
            }
            if (OC8) {
                unsigned pr = f32_to_e5m2(vr), pi = f32_to_e5m2(vi);
                ((unsigned short*)OC8)[idx] = (unsigned short)(pr | (pi << 8));
            }
        }
    }
}

// ---------------------------------------------------------------------------
// 5. Head via MFMA + fused log_softmax (unchanged).
// ---------------------------------------------------------------------------
__global__ __launch_bounds__(256) void head_mfma(
    const bf16* __restrict__ Yrb,
    const bf16* __restrict__ Yib,
    const bf16* __restrict__ Wcb,
    const float* __restrict__ bc,
    float* __restrict__ out)          // [4096][40]
{
    __shared__ __align__(16) bf16 sY[64][72];
    __shared__ __align__(16) bf16 sW[48][72];
    __shared__ float sS[64][52];

    const int tid  = threadIdx.x;
    const int wave = tid >> 6;
    const int lane = tid & 63;
    const int r0 = blockIdx.x * 64;

    f32x4 acc[3] = {};

    for (int kb = 0; kb < 512; kb += 64) {
        const bf16* src = (kb < 256) ? Yrb : Yib;
        const int koff = kb & 255;
        #pragma unroll
        for (int e = 0; e < 2; ++e) {
            int idx = tid + e * 256;             // 0..511
            int rr = idx >> 3, kk = (idx & 7) * 8;
            *(bf16x8*)&sY[rr][kk] =
                *(const bf16x8*)&src[(size_t)(r0 + rr) * FDIM + koff + kk];
        }
        #pragma unroll
        for (int e = 0; e < 2; ++e) {
            int idx = tid + e * 256;             // need 0..383
            if (idx < 384) {
                int rr = idx >> 3, kk = (idx & 7) * 8;
                *(bf16x8*)&sW[rr][kk] =
                    *(const bf16x8*)&Wcb[(size_t)rr * 512 + kb + kk];
            }
        }
        __syncthreads();
        #pragma unroll
        for (int ks = 0; ks < 2; ++ks) {
            bf16x8 a = *(const bf16x8*)&sY[wave * 16 + (lane & 15)][ks * 32 + (lane >> 4) * 8];
            #pragma unroll
            for (int n = 0; n < 3; ++n) {
                bf16x8 b = *(const bf16x8*)&sW[n * 16 + (lane & 15)][ks * 32 + (lane >> 4) * 8];
                acc[n] = __builtin_amdgcn_mfma_f32_16x16x32_bf16(a, b, acc[n], 0, 0, 0);
            }
        }
        __syncthreads();
    }

    #pragma unroll
    for (int n = 0; n < 3; ++n) {
        int col = n * 16 + (lane & 15);
        int rloc = wave * 16 + (lane >> 4) * 4;
        #pragma unroll
        for (int r = 0; r < 4; ++r)
            sS[rloc + r][col] = acc[n][r];
    }
    __syncthreads();

    if (tid < 64) {
        float mx = -INFINITY;
        #pragma unroll 8
        for (int c = 0; c < CDIM; ++c) {
            float lv = sS[tid][c] + bc[c];
            sS[tid][c] = lv;
            mx = fmaxf(mx, lv);
        }
        float se = 0.f;
        #pragma unroll 8
        for (int c = 0; c < CDIM; ++c) se += expf(sS[tid][c] - mx);
        float lse = mx + logf(se);
        #pragma unroll 8
        for (int c = 0; c < CDIM; ++c)
            out[(size_t)(r0 + tid) * CDIM + c] = sS[tid][c] - lse;
    }
}

// ---------------------------------------------------------------------------
// Launcher
// ---------------------------------------------------------------------------
extern "C" void kernel_launch(void* const* d_in, const int* in_sizes, int n_in,
                              void* d_out, int out_size, void* d_ws, size_t ws_size,
                              hipStream_t stream) {
    const float* real = (const float*)d_in[0];
    const float* imag = (const float*)d_in[1];
    const int*   edges = (const int*)d_in[2];
    const float* q    = (const float*)d_in[3];
    const float* ew   = (const float*)d_in[4];
    const float* W1   = (const float*)d_in[5];
    const float* b1   = (const float*)d_in[6];
    const float* W2   = (const float*)d_in[7];
    const float* b2   = (const float*)d_in[8];
    const float* Wc   = (const float*)d_in[9];
    const float* bc   = (const float*)d_in[10];
    float* out = (float*)d_out;

    // ---- workspace carve-up ----
    char* w = (char*)d_ws;
    int*      hkey   = (int*)w;   w += (size_t)HSIZE * 4;       // 2 MB
    float*    hval   = (float*)w; w += (size_t)HSIZE * 4;       // 2 MB
    int*      cnt    = (int*)w;   w += N_NODES * 4;
    float*    rowsum = (float*)w; w += N_NODES * 4;
    float*    colsum = (float*)w; w += N_NODES * 4;
    size_t zero_bytes = (size_t)((char*)w - (char*)d_ws);
    // Non-zeroed:
    Entry* ent  = (Entry*)w; w += (size_t)N_NODES * CAP * 16;   // 16 MB
    bf16* Xr16 = (bf16*)w; w += NF * 2;
    bf16* Xi16 = (bf16*)w; w += NF * 2;
    u8*   XC8  = (u8*)w;   w += NF * 2;                         // interleaved fp8
    bf16* Z1r  = (bf16*)w; w += NF * 2;
    bf16* Z1i  = (bf16*)w; w += NF * 2;
    u8*   Z1C8 = (u8*)w;   w += NF * 2;
    bf16* Z2r  = (bf16*)w; w += NF * 2;
    bf16* Z2i  = (bf16*)w; w += NF * 2;
    bf16* Y1rb = (bf16*)w; w += NF * 2;
    bf16* Y1ib = (bf16*)w; w += NF * 2;
    u8*   Y1C8 = (u8*)w;   w += NF * 2;
    bf16* Y2rb = (bf16*)w; w += NF * 2;
    bf16* Y2ib = (bf16*)w; w += NF * 2;
    bf16* W1t  = (bf16*)w; w += 256 * 768 * 2;
    bf16* W2t  = (bf16*)w; w += 256 * 768 * 2;
    bf16* Wcb  = (bf16*)w; w += 48 * 512 * 2;

    hipMemsetAsync(d_ws, 0, zero_bytes, stream);

    // ---- fused prep (hash insert + all casts) ----
    prep_k<<<HASH_BLOCKS + XCAST_BLOCKS + WCAST_BLOCKS, 256, 0, stream>>>(
        edges, ew, hkey, hval, rowsum, colsum,
        real, imag, W1, W2, Wc,
        Xr16, Xi16, XC8, W1t, W2t, Wcb);

    hash_to_ell<<<HSIZE / 256, 256, 0, stream>>>(hkey, hval, rowsum, colsum,
                                                 q, cnt, ent);

    dim3 gW(FDIM / 64, N_NODES / 32);   // (4, 128) -> 512 blocks, 2/CU

    // ---- Layer 1 ----
    spmm_k<<<N_NODES, 256, 0, stream>>>(cnt, ent, XC8, nullptr, nullptr,
                                        1.f, 0.f, Z1r, Z1i, Z1C8);
    spmm_k<<<N_NODES, 256, 0, stream>>>(cnt, ent, Z1C8, Xr16, Xi16,
                                        2.f, -1.f, Z2r, Z2i, nullptr);
    wapply_mfma<<<gW, 256, 0, stream>>>(Xr16, Xi16, Z1r, Z1i, Z2r, Z2i,
                                        W1t, b1,
                                        Y1rb, Y1ib,
                                        Y1C8);

    // ---- Layer 2 ----
    spmm_k<<<N_NODES, 256, 0, stream>>>(cnt, ent, Y1C8, nullptr, nullptr,
                                        1.f, 0.f, Z1r, Z1i, Z1C8);
    spmm_k<<<N_NODES, 256, 0, stream>>>(cnt, ent, Z1C8, Y1rb, Y1ib,
                                        2.f, -1.f, Z2r, Z2i, nullptr);
    wapply_mfma<<<gW, 256, 0, stream>>>(Y1rb, Y1ib, Z1r, Z1i, Z2r, Z2i,
                                        W2t, b2,
                                        Y2rb, Y2ib,
                                        nullptr);

    // ---- Head ----
    head_mfma<<<64, 256, 0, stream>>>(Y2rb, Y2ib, Wcb, bc, out);
}